// Round 2
// baseline (234.762 us; speedup 1.0000x reference)
//
#include <hip/hip_runtime.h>
#include <hip/hip_bf16.h>

typedef short s16x8 __attribute__((ext_vector_type(8)));
typedef short s16x4 __attribute__((ext_vector_type(4)));
typedef float f32x4 __attribute__((ext_vector_type(4)));
typedef __hip_bfloat16 bf16;

#define MFMA16(a, b, c) __builtin_amdgcn_mfma_f32_16x16x32_bf16((a), (b), (c), 0, 0, 0)

#define BATCH 4
#define SEQ 2048
#define NH 12
#define DH 64
#define DM 768
#define ROWS (BATCH * SEQ)       // 8192
#define QKVC (3 * DM)            // 2304
#define LOG2E 1.4426950408889634f

static __device__ inline float fast_exp2(float x) {
  float r;
  asm("v_exp_f32 %0, %1" : "=v"(r) : "v"(x));
  return r;
}
static __device__ inline unsigned pkbf16(float a, float b) {
  bf16 ha = __float2bfloat16(a), hb = __float2bfloat16(b);
  unsigned short ua, ub;
  __builtin_memcpy(&ua, &ha, 2);
  __builtin_memcpy(&ub, &hb, 2);
  return (unsigned)ua | ((unsigned)ub << 16);
}

// async global->LDS 16B copy (m97 pattern)
typedef __attribute__((address_space(3))) unsigned int lds_u32;
typedef __attribute__((address_space(1))) const unsigned int glb_u32;
static __device__ inline void gl2lds16(const void* g, void* l) {
  __builtin_amdgcn_global_load_lds((glb_u32*)g, (lds_u32*)l, 16, 0, 0);
}

// ---------------------------------------------------------------------------
// Kernel 1: fused prep. WcT [2304 col][768 k], WoT [768 e][768 k], x->bf16.
// ---------------------------------------------------------------------------
#define NWC (QKVC * DM)            // 1769472
#define NWO (DM * DM)              // 589824
#define NXC (ROWS * DM / 8)        // 786432 (8-elem chunks)
__global__ __launch_bounds__(256) void prep_all(
    const float* __restrict__ wq, const float* __restrict__ wk,
    const float* __restrict__ wv, const float* __restrict__ wo,
    const float* __restrict__ x, bf16* __restrict__ WcT,
    bf16* __restrict__ WoT, bf16* __restrict__ xb) {
  int i = blockIdx.x * 256 + threadIdx.x;
  if (i < NWC) {
    int c = i / DM, e = i % DM;
    int mat = c / DM;
    int r = c % DM;
    int n = r >> 6, h = r & 63;
    const float* W = (mat == 0) ? wq : ((mat == 1) ? wk : wv);
    WcT[i] = __float2bfloat16(W[n * (DM * DH) + e * DH + h]);
  } else if (i < NWC + NWO) {
    int j = i - NWC;
    int e = j / DM, r = j % DM;
    WoT[j] = __float2bfloat16(wo[r * DM + e]);
  } else {
    int j = i - NWC - NWO;  // 8-elem chunk of x
    const float* src = x + (size_t)j * 8;
    float4 f0 = *(const float4*)src;
    float4 f1 = *(const float4*)(src + 4);
    bf16 tmp[8];
    tmp[0] = __float2bfloat16(f0.x); tmp[1] = __float2bfloat16(f0.y);
    tmp[2] = __float2bfloat16(f0.z); tmp[3] = __float2bfloat16(f0.w);
    tmp[4] = __float2bfloat16(f1.x); tmp[5] = __float2bfloat16(f1.y);
    tmp[6] = __float2bfloat16(f1.z); tmp[7] = __float2bfloat16(f1.w);
    *(s16x8*)(xb + (size_t)j * 8) = *(const s16x8*)tmp;
  }
}

// ---------------------------------------------------------------------------
// Kernel 2: QKV projection GEMM (async staging).
// Outputs: Qb [bh][s][64] (scaled 0.125*log2e), Kb [bh][s][64], Vt [bh][h][s].
// ---------------------------------------------------------------------------
__global__ __launch_bounds__(256) void qkv_gemm(
    const bf16* __restrict__ xb, const bf16* __restrict__ WcT,
    const float* __restrict__ bQ, const float* __restrict__ bK,
    const float* __restrict__ bV, bf16* __restrict__ Qb,
    bf16* __restrict__ Kb, bf16* __restrict__ Vt) {
  __shared__ bf16 As[128 * 32];
  __shared__ bf16 Bs[128 * 32];
  const int m0 = blockIdx.x * 128;
  const int n0 = blockIdx.y * 128;
  const int tid = threadIdx.x;
  const int wave = tid >> 6, lane = tid & 63;
  const int quad = lane >> 4, l15 = lane & 15;
  const int wm = (wave & 1) * 64, wn = (wave >> 1) * 64;

  f32x4 acc[4][4] = {};

  for (int k0 = 0; k0 < DM; k0 += 32) {
    {
      int c = tid, row = c >> 2, sg = (c & 3) << 3;
      gl2lds16(xb + (size_t)(m0 + row) * DM + k0 + sg, &As[c * 8]);
      gl2lds16(WcT + (size_t)(n0 + row) * DM + k0 + sg, &Bs[c * 8]);
      c = tid + 256; row = c >> 2; sg = (c & 3) << 3;
      gl2lds16(xb + (size_t)(m0 + row) * DM + k0 + sg, &As[c * 8]);
      gl2lds16(WcT + (size_t)(n0 + row) * DM + k0 + sg, &Bs[c * 8]);
    }
    __syncthreads();
    s16x8 af[4], bfr[4];
    for (int i = 0; i < 4; i++)
      af[i] = *(const s16x8*)&As[(wm + i * 16 + l15) * 32 + quad * 8];
    for (int j = 0; j < 4; j++)
      bfr[j] = *(const s16x8*)&Bs[(wn + j * 16 + l15) * 32 + quad * 8];
    for (int i = 0; i < 4; i++)
      for (int j = 0; j < 4; j++)
        acc[i][j] = MFMA16(af[i], bfr[j], acc[i][j]);
    __syncthreads();
  }

  const int mat = n0 / DM;  // uniform per block (768 % 128 == 0)
  for (int j = 0; j < 4; j++) {
    int col = n0 + wn + j * 16 + l15;
    int cc = col - mat * DM;
    int head = cc >> 6, h = cc & 63;
    float bsv = ((mat == 0) ? bQ : (mat == 1) ? bK : bV)[cc];
    for (int i = 0; i < 4; i++) {
      int row0 = m0 + wm + i * 16 + quad * 4;
      int b = row0 >> 11;
      int s = row0 & 2047;
      int bh = b * NH + head;
      if (mat == 2) {
        s16x4 pv;
        for (int r = 0; r < 4; r++) {
          bf16 hv = __float2bfloat16(acc[i][j][r] + bsv);
          short sv; __builtin_memcpy(&sv, &hv, 2);
          pv[r] = sv;
        }
        *(s16x4*)(Vt + ((size_t)bh * DH + h) * SEQ + s) = pv;
      } else {
        const float scale = (mat == 0) ? (0.125f * LOG2E) : 1.0f;
        bf16* dst = ((mat == 0) ? Qb : Kb) + ((size_t)bh * SEQ + s) * DH + h;
        for (int r = 0; r < 4; r++)
          dst[(size_t)r * DH] = __float2bfloat16((acc[i][j][r] + bsv) * scale);
      }
    }
  }
}

// ---------------------------------------------------------------------------
// Kernel 3: flash attention (causal), balanced-pair blocks, 4 waves x 16 q.
// Block = q-tiles (qtA=31-p, qtB=p) of one bh, fused k-loop sharing K/V LDS.
// Every block: exactly 33 tile-computes -> zero tail.
// ROUND-2 CONTROLLED A/B vs round-0:
//   - LINEAR blockIdx decode restored (round-1's XCD decode reverted).
//   - PsPad restores the exact round-0 LDS footprint (27648 B) so dispatch
//     packing is identical to round-0; referenced under an opaque condition
//     so the compiler cannot eliminate the allocation.
//   - ONLY remaining diff vs round-0: P redistribution in-register via
//     permlane32_swap + permlane16_swap (no LDS round-trip, no lgkm fence).
// ---------------------------------------------------------------------------
__global__ __launch_bounds__(256) void flash_kernel(
    const bf16* __restrict__ Qb, const bf16* __restrict__ Kb,
    const bf16* __restrict__ Vt, bf16* __restrict__ Z) {
  __shared__ bf16 Ks[64 * 72];       // [key][h], padded
  __shared__ bf16 VsT[64 * 72];      // [h][key], padded
  __shared__ bf16 PsPad[4][16 * 72]; // UNUSED: LDS-footprint control (9216 B)

  const int bh = blockIdx.x >> 4;  // 0..47  (linear, as in round-0)
  const int p = blockIdx.x & 15;   // 0..15
  const int qtA = 31 - p, qtB = p;
  const int b = bh / NH, head = bh % NH;
  const int tid = threadIdx.x;
  const int wave = tid >> 6, lane = tid & 63;
  const int quad = lane >> 4, l15 = lane & 15;
  const int qwA = qtA * 64 + wave * 16;  // this wave's 16 q rows (tile A)
  const int qwB = qtB * 64 + wave * 16;  // tile B

  // opaque-false touch: keeps PsPad allocated without executing
  if ((int)blockIdx.x == -1) PsPad[wave][tid] = __float2bfloat16(0.f);

  const bf16* Kbase = Kb + (size_t)bh * SEQ * DH;
  const bf16* Vbase = Vt + (size_t)bh * DH * SEQ;

  // Q as B-operand: lane n=l15 -> q=qw+l15, k -> h (pre-scaled 0.125*log2e).
  s16x8 bqA[2], bqB[2];
  for (int ks = 0; ks < 2; ks++) {
    bqA[ks] = *(const s16x8*)(Qb +
        ((size_t)bh * SEQ + qwA + l15) * DH + ks * 32 + quad * 8);
    bqB[ks] = *(const s16x8*)(Qb +
        ((size_t)bh * SEQ + qwB + l15) * DH + ks * 32 + quad * 8);
  }

  f32x4 oA[4] = {}, oB[4] = {};
  float lA = 0.f, lB = 0.f;

  // staging: 256 threads x 2 chunks (16B) per matrix
  s16x8 kr[2], vr[2];
  auto load_tile = [&](int kt) {
    const int kbase = kt * 64;
    for (int u = 0; u < 2; u++) {
      int c = tid + u * 256;
      int row = c >> 3, seg = (c & 7) << 3;
      kr[u] = *(const s16x8*)(Kbase + (size_t)(kbase + row) * DH + seg);
      vr[u] = *(const s16x8*)(Vbase + (size_t)row * SEQ + kbase + seg);
    }
  };
  auto store_tile = [&]() {
    for (int u = 0; u < 2; u++) {
      int c = tid + u * 256;
      int row = c >> 3, seg = (c & 7) << 3;
      *(s16x8*)&Ks[row * 72 + seg] = kr[u];
      *(s16x8*)&VsT[row * 72 + seg] = vr[u];
    }
  };

  auto compute = [&](int kt, const s16x8 bq[2], f32x4 o[4], float& l_i,
                     int qw, bool diag) {
    const int kbase = kt * 64;
    // S^T[key][q]: A=K (m=key), B=Q (n=q). s[ktf]: key=kbase+ktf*16+quad*4+r,
    // q = qw + l15.
    f32x4 s[4] = {};
    for (int ks = 0; ks < 2; ks++) {
      s16x8 ak[4];
      for (int ktf = 0; ktf < 4; ktf++)
        ak[ktf] = *(const s16x8*)&Ks[(ktf * 16 + l15) * 72 + ks * 32 + quad * 8];
      for (int ktf = 0; ktf < 4; ktf++)
        s[ktf] = MFMA16(ak[ktf], bq[ks], s[ktf]);
    }

    if (diag) {  // causal mask on the diagonal tile
      int qg = qw + l15;
      for (int ktf = 0; ktf < 4; ktf++)
        for (int r = 0; r < 4; r++) {
          int kg = kbase + ktf * 16 + quad * 4 + r;
          if (kg > qg) s[ktf][r] = -1e30f;
        }
    }

    // softmax numerator: p = exp2(s) (bounded; masked -> 0); per-lane partial l
    // and pack pairs: w[ktf][j] holds keys (16*ktf + 4*quad + 2j, +1) as bf16x2
    float rs = 0.f;
    unsigned w[4][2];
    for (int ktf = 0; ktf < 4; ktf++) {
      float p0 = fast_exp2(s[ktf][0]);
      float p1 = fast_exp2(s[ktf][1]);
      float p2 = fast_exp2(s[ktf][2]);
      float p3 = fast_exp2(s[ktf][3]);
      rs += (p0 + p1) + (p2 + p3);
      w[ktf][0] = pkbf16(p0, p1);
      w[ktf][1] = pkbf16(p2, p3);
    }
    l_i += rs;

    // In-register cross-quad redistribution to the PV A-fragment layout.
    // Target lane (quad_t,l15), slice ks2, dword d needs source
    //   quad_s = 2*(quad_t&1) + (d>>1), ktf = 2*ks2 + (quad_t>>1), j = d&1.
    // permlane32_swap(u,v): u'={u.lo32,v.lo32}, v'={u.hi32,v.hi32}
    // permlane16_swap(a,b): a'={a.r0,b.r0,a.r2,b.r2}, b'={a.r1,b.r1,a.r3,b.r3}
    // => P0[j]=[u_q0,u_q2,v_q0,v_q2] (d=j), P1[j]=[u_q1,u_q3,v_q1,v_q3] (d=2+j)
    s16x8 ap[2];
    for (int ks2 = 0; ks2 < 2; ks2++) {
      int dw[4];
      for (int j = 0; j < 2; j++) {
        auto t = __builtin_amdgcn_permlane32_swap(
            (int)w[2 * ks2][j], (int)w[2 * ks2 + 1][j], false, false);
        auto pq = __builtin_amdgcn_permlane16_swap(t[0], t[1], false, false);
        dw[j] = pq[0];
        dw[2 + j] = pq[1];
      }
      __builtin_memcpy(&ap[ks2], dw, 16);
    }

    // PV: o[q][h] += P[q][key] * V^T[h][key]
    for (int ks2 = 0; ks2 < 2; ks2++) {
      for (int hf = 0; hf < 4; hf++) {
        s16x8 bv =
            *(const s16x8*)&VsT[(hf * 16 + l15) * 72 + ks2 * 32 + quad * 8];
        o[hf] = MFMA16(ap[ks2], bv, o[hf]);
      }
    }
  };

  load_tile(0);
  for (int kt = 0; kt <= qtA; kt++) {
    __syncthreads();
    store_tile();
    __syncthreads();
    if (kt < qtA) load_tile(kt + 1);
    compute(kt, bqA, oA, lA, qwA, kt == qtA);
    if (kt <= qtB) compute(kt, bqB, oB, lB, qwB, kt == qtB);
  }

  // epilogue: reduce l across quads, broadcast 1/l to C/D rows, write Z
  auto epilogue = [&](f32x4 o[4], float l_i, int qw) {
    float lv = l_i;
    lv += __shfl_xor(lv, 16, 64);
    lv += __shfl_xor(lv, 32, 64);
    float linv = 1.f / lv;
    for (int r = 0; r < 4; r++) {
      float li = __shfl(linv, (lane & 48) | (quad * 4 + r), 64);
      int q = qw + quad * 4 + r;
      for (int hf = 0; hf < 4; hf++) {
        Z[((size_t)b * SEQ + q) * DM + head * DH + hf * 16 + l15] =
            __float2bfloat16(o[hf][r] * li);
      }
    }
  };
  epilogue(oA, lA, qwA);
  epilogue(oB, lB, qwB);
}

// ---------------------------------------------------------------------------
// Kernel 4: output projection (async staging).
// ---------------------------------------------------------------------------
__global__ __launch_bounds__(256) void out_gemm(
    const bf16* __restrict__ Z, const bf16* __restrict__ WoT,
    const float* __restrict__ bO, float* __restrict__ out) {
  __shared__ bf16 As[128 * 32];
  __shared__ bf16 Bs[128 * 32];
  const int m0 = blockIdx.x * 128;
  const int n0 = blockIdx.y * 128;
  const int tid = threadIdx.x;
  const int wave = tid >> 6, lane = tid & 63;
  const int quad = lane >> 4, l15 = lane & 15;
  const int wm = (wave & 1) * 64, wn = (wave >> 1) * 64;

  f32x4 acc[4][4] = {};

  for (int k0 = 0; k0 < DM; k0 += 32) {
    {
      int c = tid, row = c >> 2, sg = (c & 3) << 3;
      gl2lds16(Z + (size_t)(m0 + row) * DM + k0 + sg, &As[c * 8]);
      gl2lds16(WoT + (size_t)(n0 + row) * DM + k0 + sg, &Bs[c * 8]);
      c = tid + 256; row = c >> 2; sg = (c & 3) << 3;
      gl2lds16(Z + (size_t)(m0 + row) * DM + k0 + sg, &As[c * 8]);
      gl2lds16(WoT + (size_t)(n0 + row) * DM + k0 + sg, &Bs[c * 8]);
    }
    __syncthreads();
    s16x8 af[4], bfr[4];
    for (int i = 0; i < 4; i++)
      af[i] = *(const s16x8*)&As[(wm + i * 16 + l15) * 32 + quad * 8];
    for (int j = 0; j < 4; j++)
      bfr[j] = *(const s16x8*)&Bs[(wn + j * 16 + l15) * 32 + quad * 8];
    for (int i = 0; i < 4; i++)
      for (int j = 0; j < 4; j++)
        acc[i][j] = MFMA16(af[i], bfr[j], acc[i][j]);
    __syncthreads();
  }

  for (int j = 0; j < 4; j++) {
    int col = n0 + wn + j * 16 + l15;
    float bv = bO[col];
    for (int i = 0; i < 4; i++)
      for (int r = 0; r < 4; r++) {
        int row = m0 + wm + i * 16 + quad * 4 + r;
        out[(size_t)row * DM + col] = acc[i][j][r] + bv;
      }
  }
}

// ---------------------------------------------------------------------------
extern "C" void kernel_launch(void* const* d_in, const int* in_sizes, int n_in,
                              void* d_out, int out_size, void* d_ws,
                              size_t ws_size, hipStream_t stream) {
  const float* x  = (const float*)d_in[0];
  const float* wq = (const float*)d_in[1];
  const float* wk = (const float*)d_in[2];
  const float* wv = (const float*)d_in[3];
  const float* wo = (const float*)d_in[4];
  const float* bq = (const float*)d_in[5];
  const float* bk = (const float*)d_in[6];
  const float* bv = (const float*)d_in[7];
  const float* bo = (const float*)d_in[8];
  float* out = (float*)d_out;

  bf16* WcT = (bf16*)d_ws;                    // 2304*768
  bf16* WoT = WcT + (size_t)QKVC * DM;        //  768*768
  bf16* Qb  = WoT + (size_t)DM * DM;          // 8192*768
  bf16* Kb  = Qb + (size_t)ROWS * DM;         // 8192*768
  bf16* Vt  = Kb + (size_t)ROWS * DM;         // 8192*768 ([bh][h][s])
  bf16* xbZ = Vt + (size_t)ROWS * DM;         // 8192*768 (xb, then Z)

  prep_all<<<(NWC + NWO + NXC) / 256, 256, 0, stream>>>(
      wq, wk, wv, wo, x, WcT, WoT, xbZ);
  qkv_gemm<<<dim3(ROWS / 128, QKVC / 128), 256, 0, stream>>>(
      xbZ, WcT, bq, bk, bv, Qb, Kb, Vt);
  flash_kernel<<<48 * 16, 256, 0, stream>>>(Qb, Kb, Vt, xbZ);
  out_gemm<<<dim3(ROWS / 128, DM / 128), 256, 0, stream>>>(xbZ, WoT, bo, out);
}

// Round 3
// 220.498 us; speedup vs baseline: 1.0647x; 1.0647x over previous
//
#include <hip/hip_runtime.h>
#include <hip/hip_bf16.h>

typedef short s16x8 __attribute__((ext_vector_type(8)));
typedef short s16x4 __attribute__((ext_vector_type(4)));
typedef float f32x4 __attribute__((ext_vector_type(4)));
typedef __hip_bfloat16 bf16;

#define MFMA16(a, b, c) __builtin_amdgcn_mfma_f32_16x16x32_bf16((a), (b), (c), 0, 0, 0)

#define BATCH 4
#define SEQ 2048
#define NH 12
#define DH 64
#define DM 768
#define ROWS (BATCH * SEQ)       // 8192
#define QKVC (3 * DM)            // 2304
#define LOG2E 1.4426950408889634f

static __device__ inline float fast_exp2(float x) {
  float r;
  asm("v_exp_f32 %0, %1" : "=v"(r) : "v"(x));
  return r;
}
static __device__ inline unsigned pkbf16(float a, float b) {
  bf16 ha = __float2bfloat16(a), hb = __float2bfloat16(b);
  unsigned short ua, ub;
  __builtin_memcpy(&ua, &ha, 2);
  __builtin_memcpy(&ub, &hb, 2);
  return (unsigned)ua | ((unsigned)ub << 16);
}

// async global->LDS 16B copy (m97 pattern)
typedef __attribute__((address_space(3))) unsigned int lds_u32;
typedef __attribute__((address_space(1))) const unsigned int glb_u32;
static __device__ inline void gl2lds16(const void* g, void* l) {
  __builtin_amdgcn_global_load_lds((glb_u32*)g, (lds_u32*)l, 16, 0, 0);
}

// ---------------------------------------------------------------------------
// Kernel 1: fused prep. WcT [2304 col][768 k], WoT [768 e][768 k], x->bf16.
// ---------------------------------------------------------------------------
#define NWC (QKVC * DM)            // 1769472
#define NWO (DM * DM)              // 589824
#define NXC (ROWS * DM / 8)        // 786432 (8-elem chunks)
__global__ __launch_bounds__(256) void prep_all(
    const float* __restrict__ wq, const float* __restrict__ wk,
    const float* __restrict__ wv, const float* __restrict__ wo,
    const float* __restrict__ x, bf16* __restrict__ WcT,
    bf16* __restrict__ WoT, bf16* __restrict__ xb) {
  int i = blockIdx.x * 256 + threadIdx.x;
  if (i < NWC) {
    int c = i / DM, e = i % DM;
    int mat = c / DM;
    int r = c % DM;
    int n = r >> 6, h = r & 63;
    const float* W = (mat == 0) ? wq : ((mat == 1) ? wk : wv);
    WcT[i] = __float2bfloat16(W[n * (DM * DH) + e * DH + h]);
  } else if (i < NWC + NWO) {
    int j = i - NWC;
    int e = j / DM, r = j % DM;
    WoT[j] = __float2bfloat16(wo[r * DM + e]);
  } else {
    int j = i - NWC - NWO;  // 8-elem chunk of x
    const float* src = x + (size_t)j * 8;
    float4 f0 = *(const float4*)src;
    float4 f1 = *(const float4*)(src + 4);
    bf16 tmp[8];
    tmp[0] = __float2bfloat16(f0.x); tmp[1] = __float2bfloat16(f0.y);
    tmp[2] = __float2bfloat16(f0.z); tmp[3] = __float2bfloat16(f0.w);
    tmp[4] = __float2bfloat16(f1.x); tmp[5] = __float2bfloat16(f1.y);
    tmp[6] = __float2bfloat16(f1.z); tmp[7] = __float2bfloat16(f1.w);
    *(s16x8*)(xb + (size_t)j * 8) = *(const s16x8*)tmp;
  }
}

// ---------------------------------------------------------------------------
// Kernel 2: QKV projection GEMM.
// T3-minimum 2-phase double-buffer: stage(t+1) issued BEFORE compute(t);
// single vmcnt(0)+barrier per K-step (was: stage -> barrier -> compute ->
// barrier, which drained the async loads immediately and cost 2 barriers).
// Outputs: Qb [bh][s][64] (scaled 0.125*log2e), Kb [bh][s][64], Vt [bh][h][s].
// ---------------------------------------------------------------------------
__global__ __launch_bounds__(256) void qkv_gemm(
    const bf16* __restrict__ xb, const bf16* __restrict__ WcT,
    const float* __restrict__ bQ, const float* __restrict__ bK,
    const float* __restrict__ bV, bf16* __restrict__ Qb,
    bf16* __restrict__ Kb, bf16* __restrict__ Vt) {
  __shared__ bf16 As[2][128 * 32];
  __shared__ bf16 Bs[2][128 * 32];
  const int m0 = blockIdx.x * 128;
  const int n0 = blockIdx.y * 128;
  const int tid = threadIdx.x;
  const int wave = tid >> 6, lane = tid & 63;
  const int quad = lane >> 4, l15 = lane & 15;
  const int wm = (wave & 1) * 64, wn = (wave >> 1) * 64;

  const int r0 = tid >> 2, sg0 = (tid & 3) << 3;
  const int c1 = tid + 256, r1 = c1 >> 2, sg1 = (c1 & 3) << 3;

  auto stage = [&](int k0, int buf) {
    gl2lds16(xb + (size_t)(m0 + r0) * DM + k0 + sg0, &As[buf][tid * 8]);
    gl2lds16(WcT + (size_t)(n0 + r0) * DM + k0 + sg0, &Bs[buf][tid * 8]);
    gl2lds16(xb + (size_t)(m0 + r1) * DM + k0 + sg1, &As[buf][c1 * 8]);
    gl2lds16(WcT + (size_t)(n0 + r1) * DM + k0 + sg1, &Bs[buf][c1 * 8]);
  };

  f32x4 acc[4][4] = {};

  stage(0, 0);
  __syncthreads();  // tile 0 resident
  int cur = 0;
  const int NT = DM / 32;  // 24
  for (int t = 0; t < NT; ++t) {
    if (t + 1 < NT) stage((t + 1) * 32, cur ^ 1);  // prefetch under compute
    s16x8 af[4], bfr[4];
    for (int i = 0; i < 4; i++)
      af[i] = *(const s16x8*)&As[cur][(wm + i * 16 + l15) * 32 + quad * 8];
    for (int j = 0; j < 4; j++)
      bfr[j] = *(const s16x8*)&Bs[cur][(wn + j * 16 + l15) * 32 + quad * 8];
    for (int i = 0; i < 4; i++)
      for (int j = 0; j < 4; j++)
        acc[i][j] = MFMA16(af[i], bfr[j], acc[i][j]);
    __syncthreads();  // drains prefetch (vmcnt 0) + protects buf reuse
    cur ^= 1;
  }

  const int mat = n0 / DM;  // uniform per block (768 % 128 == 0)
  for (int j = 0; j < 4; j++) {
    int col = n0 + wn + j * 16 + l15;
    int cc = col - mat * DM;
    int head = cc >> 6, h = cc & 63;
    float bsv = ((mat == 0) ? bQ : (mat == 1) ? bK : bV)[cc];
    for (int i = 0; i < 4; i++) {
      int row0 = m0 + wm + i * 16 + quad * 4;
      int b = row0 >> 11;
      int s = row0 & 2047;
      int bh = b * NH + head;
      if (mat == 2) {
        s16x4 pv;
        for (int r = 0; r < 4; r++) {
          bf16 hv = __float2bfloat16(acc[i][j][r] + bsv);
          short sv; __builtin_memcpy(&sv, &hv, 2);
          pv[r] = sv;
        }
        *(s16x4*)(Vt + ((size_t)bh * DH + h) * SEQ + s) = pv;
      } else {
        const float scale = (mat == 0) ? (0.125f * LOG2E) : 1.0f;
        bf16* dst = ((mat == 0) ? Qb : Kb) + ((size_t)bh * SEQ + s) * DH + h;
        for (int r = 0; r < 4; r++)
          dst[(size_t)r * DH] = __float2bfloat16((acc[i][j][r] + bsv) * scale);
      }
    }
  }
}

// ---------------------------------------------------------------------------
// Kernel 3: flash attention (causal) — EXACT round-0 configuration restored
// (58.6 us measured): LDS P round-trip, linear decode, LDS 27648 B.
// ---------------------------------------------------------------------------
__global__ __launch_bounds__(256) void flash_kernel(
    const bf16* __restrict__ Qb, const bf16* __restrict__ Kb,
    const bf16* __restrict__ Vt, bf16* __restrict__ Z) {
  __shared__ bf16 Ks[64 * 72];    // [key][h], padded
  __shared__ bf16 VsT[64 * 72];   // [h][key], padded
  __shared__ bf16 Ps[4][16 * 72]; // per-wave P [q][key], padded

  const int bh = blockIdx.x >> 4;  // 0..47
  const int p = blockIdx.x & 15;   // 0..15
  const int qtA = 31 - p, qtB = p;
  const int b = bh / NH, head = bh % NH;
  const int tid = threadIdx.x;
  const int wave = tid >> 6, lane = tid & 63;
  const int quad = lane >> 4, l15 = lane & 15;
  const int qwA = qtA * 64 + wave * 16;  // this wave's 16 q rows (tile A)
  const int qwB = qtB * 64 + wave * 16;  // tile B

  const bf16* Kbase = Kb + (size_t)bh * SEQ * DH;
  const bf16* Vbase = Vt + (size_t)bh * DH * SEQ;

  // Q as B-operand: lane n=l15 -> q=qw+l15, k -> h (pre-scaled 0.125*log2e).
  s16x8 bqA[2], bqB[2];
  for (int ks = 0; ks < 2; ks++) {
    bqA[ks] = *(const s16x8*)(Qb +
        ((size_t)bh * SEQ + qwA + l15) * DH + ks * 32 + quad * 8);
    bqB[ks] = *(const s16x8*)(Qb +
        ((size_t)bh * SEQ + qwB + l15) * DH + ks * 32 + quad * 8);
  }

  f32x4 oA[4] = {}, oB[4] = {};
  float lA = 0.f, lB = 0.f;

  // staging: 256 threads x 2 chunks (16B) per matrix
  s16x8 kr[2], vr[2];
  auto load_tile = [&](int kt) {
    const int kbase = kt * 64;
    for (int u = 0; u < 2; u++) {
      int c = tid + u * 256;
      int row = c >> 3, seg = (c & 7) << 3;
      kr[u] = *(const s16x8*)(Kbase + (size_t)(kbase + row) * DH + seg);
      vr[u] = *(const s16x8*)(Vbase + (size_t)row * SEQ + kbase + seg);
    }
  };
  auto store_tile = [&]() {
    for (int u = 0; u < 2; u++) {
      int c = tid + u * 256;
      int row = c >> 3, seg = (c & 7) << 3;
      *(s16x8*)&Ks[row * 72 + seg] = kr[u];
      *(s16x8*)&VsT[row * 72 + seg] = vr[u];
    }
  };

  auto compute = [&](int kt, const s16x8 bq[2], f32x4 o[4], float& l_i,
                     int qw, bool diag) {
    const int kbase = kt * 64;
    // S^T[key][q]: A=K (m=key), B=Q (n=q). s[ktf]: key=kbase+ktf*16+quad*4+r,
    // q = qw + l15.
    f32x4 s[4] = {};
    for (int ks = 0; ks < 2; ks++) {
      s16x8 ak[4];
      for (int ktf = 0; ktf < 4; ktf++)
        ak[ktf] = *(const s16x8*)&Ks[(ktf * 16 + l15) * 72 + ks * 32 + quad * 8];
      for (int ktf = 0; ktf < 4; ktf++)
        s[ktf] = MFMA16(ak[ktf], bq[ks], s[ktf]);
    }

    if (diag) {  // causal mask on the diagonal tile
      int qg = qw + l15;
      for (int ktf = 0; ktf < 4; ktf++)
        for (int r = 0; r < 4; r++) {
          int kg = kbase + ktf * 16 + quad * 4 + r;
          if (kg > qg) s[ktf][r] = -1e30f;
        }
    }

    // softmax numerator: p = exp2(s) (bounded; masked -> 0); per-lane partial l
    float rs = 0.f;
    for (int ktf = 0; ktf < 4; ktf++)
      for (int r = 0; r < 4; r++) {
        float pv = fast_exp2(s[ktf][r]);
        s[ktf][r] = pv;
        rs += pv;
      }
    l_i += rs;

    // P -> per-wave LDS in [q][key] (A-operand friendly)
    bf16* Pw = Ps[wave];
    for (int ktf = 0; ktf < 4; ktf++) {
      uint2 w;
      w.x = pkbf16(s[ktf][0], s[ktf][1]);
      w.y = pkbf16(s[ktf][2], s[ktf][3]);
      *(uint2*)&Pw[l15 * 72 + ktf * 16 + quad * 4] = w;
    }
    asm volatile("s_waitcnt lgkmcnt(0)" ::: "memory");

    // PV: o[q][h] += P[q][key] * V^T[h][key]
    for (int ks2 = 0; ks2 < 2; ks2++) {
      s16x8 ap = *(const s16x8*)&Pw[l15 * 72 + ks2 * 32 + quad * 8];
      for (int hf = 0; hf < 4; hf++) {
        s16x8 bv =
            *(const s16x8*)&VsT[(hf * 16 + l15) * 72 + ks2 * 32 + quad * 8];
        o[hf] = MFMA16(ap, bv, o[hf]);
      }
    }
  };

  load_tile(0);
  for (int kt = 0; kt <= qtA; kt++) {
    __syncthreads();
    store_tile();
    __syncthreads();
    if (kt < qtA) load_tile(kt + 1);
    compute(kt, bqA, oA, lA, qwA, kt == qtA);
    if (kt <= qtB) compute(kt, bqB, oB, lB, qwB, kt == qtB);
  }

  // epilogue: reduce l across quads, broadcast 1/l to C/D rows, write Z
  auto epilogue = [&](f32x4 o[4], float l_i, int qw) {
    float lv = l_i;
    lv += __shfl_xor(lv, 16, 64);
    lv += __shfl_xor(lv, 32, 64);
    float linv = 1.f / lv;
    for (int r = 0; r < 4; r++) {
      float li = __shfl(linv, (lane & 48) | (quad * 4 + r), 64);
      int q = qw + quad * 4 + r;
      for (int hf = 0; hf < 4; hf++) {
        Z[((size_t)b * SEQ + q) * DM + head * DH + hf * 16 + l15] =
            __float2bfloat16(o[hf][r] * li);
      }
    }
  };
  epilogue(oA, lA, qwA);
  epilogue(oB, lB, qwB);
}

// ---------------------------------------------------------------------------
// Kernel 4: output projection (2-phase double-buffer, same as qkv_gemm).
// ---------------------------------------------------------------------------
__global__ __launch_bounds__(256) void out_gemm(
    const bf16* __restrict__ Z, const bf16* __restrict__ WoT,
    const float* __restrict__ bO, float* __restrict__ out) {
  __shared__ bf16 As[2][128 * 32];
  __shared__ bf16 Bs[2][128 * 32];
  const int m0 = blockIdx.x * 128;
  const int n0 = blockIdx.y * 128;
  const int tid = threadIdx.x;
  const int wave = tid >> 6, lane = tid & 63;
  const int quad = lane >> 4, l15 = lane & 15;
  const int wm = (wave & 1) * 64, wn = (wave >> 1) * 64;

  const int r0 = tid >> 2, sg0 = (tid & 3) << 3;
  const int c1 = tid + 256, r1 = c1 >> 2, sg1 = (c1 & 3) << 3;

  auto stage = [&](int k0, int buf) {
    gl2lds16(Z + (size_t)(m0 + r0) * DM + k0 + sg0, &As[buf][tid * 8]);
    gl2lds16(WoT + (size_t)(n0 + r0) * DM + k0 + sg0, &Bs[buf][tid * 8]);
    gl2lds16(Z + (size_t)(m0 + r1) * DM + k0 + sg1, &As[buf][c1 * 8]);
    gl2lds16(WoT + (size_t)(n0 + r1) * DM + k0 + sg1, &Bs[buf][c1 * 8]);
  };

  f32x4 acc[4][4] = {};

  stage(0, 0);
  __syncthreads();
  int cur = 0;
  const int NT = DM / 32;  // 24
  for (int t = 0; t < NT; ++t) {
    if (t + 1 < NT) stage((t + 1) * 32, cur ^ 1);
    s16x8 af[4], bfr[4];
    for (int i = 0; i < 4; i++)
      af[i] = *(const s16x8*)&As[cur][(wm + i * 16 + l15) * 32 + quad * 8];
    for (int j = 0; j < 4; j++)
      bfr[j] = *(const s16x8*)&Bs[cur][(wn + j * 16 + l15) * 32 + quad * 8];
    for (int i = 0; i < 4; i++)
      for (int j = 0; j < 4; j++)
        acc[i][j] = MFMA16(af[i], bfr[j], acc[i][j]);
    __syncthreads();
    cur ^= 1;
  }

  for (int j = 0; j < 4; j++) {
    int col = n0 + wn + j * 16 + l15;
    float bv = bO[col];
    for (int i = 0; i < 4; i++)
      for (int r = 0; r < 4; r++) {
        int row = m0 + wm + i * 16 + quad * 4 + r;
        out[(size_t)row * DM + col] = acc[i][j][r] + bv;
      }
  }
}

// ---------------------------------------------------------------------------
extern "C" void kernel_launch(void* const* d_in, const int* in_sizes, int n_in,
                              void* d_out, int out_size, void* d_ws,
                              size_t ws_size, hipStream_t stream) {
  const float* x  = (const float*)d_in[0];
  const float* wq = (const float*)d_in[1];
  const float* wk = (const float*)d_in[2];
  const float* wv = (const float*)d_in[3];
  const float* wo = (const float*)d_in[4];
  const float* bq = (const float*)d_in[5];
  const float* bk = (const float*)d_in[6];
  const float* bv = (const float*)d_in[7];
  const float* bo = (const float*)d_in[8];
  float* out = (float*)d_out;

  bf16* WcT = (bf16*)d_ws;                    // 2304*768
  bf16* WoT = WcT + (size_t)QKVC * DM;        //  768*768
  bf16* Qb  = WoT + (size_t)DM * DM;          // 8192*768
  bf16* Kb  = Qb + (size_t)ROWS * DM;         // 8192*768
  bf16* Vt  = Kb + (size_t)ROWS * DM;         // 8192*768 ([bh][h][s])
  bf16* xbZ = Vt + (size_t)ROWS * DM;         // 8192*768 (xb, then Z)

  prep_all<<<(NWC + NWO + NXC) / 256, 256, 0, stream>>>(
      wq, wk, wv, wo, x, WcT, WoT, xbZ);
  qkv_gemm<<<dim3(ROWS / 128, QKVC / 128), 256, 0, stream>>>(
      xbZ, WcT, bq, bk, bv, Qb, Kb, Vt);
  flash_kernel<<<48 * 16, 256, 0, stream>>>(Qb, Kb, Vt, xbZ);
  out_gemm<<<dim3(ROWS / 128, DM / 128), 256, 0, stream>>>(xbZ, WoT, bo, out);
}

// Round 4
// 211.683 us; speedup vs baseline: 1.1090x; 1.0416x over previous
//
#include <hip/hip_runtime.h>
#include <hip/hip_bf16.h>

typedef short s16x8 __attribute__((ext_vector_type(8)));
typedef short s16x4 __attribute__((ext_vector_type(4)));
typedef float f32x4 __attribute__((ext_vector_type(4)));
typedef __hip_bfloat16 bf16;

#define MFMA16(a, b, c) __builtin_amdgcn_mfma_f32_16x16x32_bf16((a), (b), (c), 0, 0, 0)

#define BATCH 4
#define SEQ 2048
#define NH 12
#define DH 64
#define DM 768
#define ROWS (BATCH * SEQ)       // 8192
#define QKVC (3 * DM)            // 2304
#define LOG2E 1.4426950408889634f

static __device__ inline float fast_exp2(float x) {
  float r;
  asm("v_exp_f32 %0, %1" : "=v"(r) : "v"(x));
  return r;
}
static __device__ inline unsigned pkbf16(float a, float b) {
  bf16 ha = __float2bfloat16(a), hb = __float2bfloat16(b);
  unsigned short ua, ub;
  __builtin_memcpy(&ua, &ha, 2);
  __builtin_memcpy(&ub, &hb, 2);
  return (unsigned)ua | ((unsigned)ub << 16);
}

// async global->LDS 16B copy (m97 pattern)
typedef __attribute__((address_space(3))) unsigned int lds_u32;
typedef __attribute__((address_space(1))) const unsigned int glb_u32;
static __device__ inline void gl2lds16(const void* g, void* l) {
  __builtin_amdgcn_global_load_lds((glb_u32*)g, (lds_u32*)l, 16, 0, 0);
}

// ---------------------------------------------------------------------------
// Kernel 1: fused prep, now with COALESCED weight transposes.
//   blocks [0,432):   WcT tiles — 3 mats x 12 heads x 12 e-tiles, 64x64 each
//   blocks [432,576): WoT tiles — 12 r-tiles x 12 e-tiles
//   blocks [576,3648): x -> bf16 elementwise (8 elems/thread, coalesced)
// Each transpose block: coalesced float4 reads -> LDS [colT][rowT] (pad 72)
// -> coalesced 16-B bf16 writes. Output layouts identical to before.
// ---------------------------------------------------------------------------
#define NTWC 432
#define NTWO 144
#define NXB  3072                  // (ROWS*DM/8)/256
__global__ __launch_bounds__(256) void prep_all(
    const float* __restrict__ wq, const float* __restrict__ wk,
    const float* __restrict__ wv, const float* __restrict__ wo,
    const float* __restrict__ x, bf16* __restrict__ WcT,
    bf16* __restrict__ WoT, bf16* __restrict__ xb) {
  __shared__ bf16 T[64 * 72];
  const int tid = threadIdx.x;
  const int blk = blockIdx.x;

  if (blk < NTWC + NTWO) {
    // -------- 64x64 transpose: dst[b][a] = src[a][b], both sides coalesced
    const float* src;
    bf16* dst;
    int sstride;
    if (blk < NTWC) {
      int mat = blk / 144, rem = blk % 144;
      int n = rem / 12, et = rem % 12;
      const float* W = (mat == 0) ? wq : ((mat == 1) ? wk : wv);
      src = W + (size_t)n * (DM * DH) + (size_t)(et * 64) * DH;  // [e][h]
      sstride = DH;
      int c0 = mat * DM + n * 64;
      dst = WcT + (size_t)c0 * DM + et * 64;                     // [h][e]
    } else {
      int t2 = blk - NTWC;
      int rt = t2 / 12, et = t2 % 12;
      src = wo + (size_t)(rt * 64) * DM + et * 64;               // [r][e]
      sstride = DM;
      dst = WoT + (size_t)(et * 64) * DM + rt * 64;              // [e][r]
    }
    for (int p = 0; p < 4; ++p) {
      int a = p * 16 + (tid >> 4);
      int b4 = (tid & 15) << 2;
      float4 v = *(const float4*)(src + (size_t)a * sstride + b4);
      T[(b4 + 0) * 72 + a] = __float2bfloat16(v.x);
      T[(b4 + 1) * 72 + a] = __float2bfloat16(v.y);
      T[(b4 + 2) * 72 + a] = __float2bfloat16(v.z);
      T[(b4 + 3) * 72 + a] = __float2bfloat16(v.w);
    }
    __syncthreads();
    for (int k = 0; k < 2; ++k) {
      int idx = tid + k * 256;
      int bb = idx >> 3, aq = (idx & 7) << 3;
      *(s16x8*)(dst + (size_t)bb * DM + aq) = *(const s16x8*)&T[bb * 72 + aq];
    }
  } else {
    // -------- x -> bf16, 8-elem chunks
    int j = (blk - NTWC - NTWO) * 256 + tid;
    const float* src = x + (size_t)j * 8;
    float4 f0 = *(const float4*)src;
    float4 f1 = *(const float4*)(src + 4);
    bf16 tmp[8];
    tmp[0] = __float2bfloat16(f0.x); tmp[1] = __float2bfloat16(f0.y);
    tmp[2] = __float2bfloat16(f0.z); tmp[3] = __float2bfloat16(f0.w);
    tmp[4] = __float2bfloat16(f1.x); tmp[5] = __float2bfloat16(f1.y);
    tmp[6] = __float2bfloat16(f1.z); tmp[7] = __float2bfloat16(f1.w);
    *(s16x8*)(xb + (size_t)j * 8) = *(const s16x8*)tmp;
  }
}

// ---------------------------------------------------------------------------
// Kernel 2: QKV projection GEMM (2-phase double-buffer, kept from round 3).
// NEW: mat==2 (V) epilogue transposes the 128x128 tile through the dead
// staging LDS so Vt stores are 16-B contiguous (was: 8-B stores at 4 KB
// stride/lane). Q/K epilogues unchanged. Numerics bit-identical.
// ---------------------------------------------------------------------------
__global__ __launch_bounds__(256) void qkv_gemm(
    const bf16* __restrict__ xb, const bf16* __restrict__ WcT,
    const float* __restrict__ bQ, const float* __restrict__ bK,
    const float* __restrict__ bV, bf16* __restrict__ Qb,
    bf16* __restrict__ Kb, bf16* __restrict__ Vt) {
  __shared__ bf16 smem[16384];  // As[2][4096] | Bs[2][4096]  (32 KB)
  bf16* As = smem;
  bf16* Bs = smem + 8192;
  const int m0 = blockIdx.x * 128;
  const int n0 = blockIdx.y * 128;
  const int tid = threadIdx.x;
  const int wave = tid >> 6, lane = tid & 63;
  const int quad = lane >> 4, l15 = lane & 15;
  const int wm = (wave & 1) * 64, wn = (wave >> 1) * 64;

  const int r0 = tid >> 2, sg0 = (tid & 3) << 3;
  const int c1 = tid + 256, r1 = c1 >> 2, sg1 = (c1 & 3) << 3;

  auto stage = [&](int k0, int buf) {
    gl2lds16(xb + (size_t)(m0 + r0) * DM + k0 + sg0, As + buf * 4096 + tid * 8);
    gl2lds16(WcT + (size_t)(n0 + r0) * DM + k0 + sg0, Bs + buf * 4096 + tid * 8);
    gl2lds16(xb + (size_t)(m0 + r1) * DM + k0 + sg1, As + buf * 4096 + c1 * 8);
    gl2lds16(WcT + (size_t)(n0 + r1) * DM + k0 + sg1, Bs + buf * 4096 + c1 * 8);
  };

  f32x4 acc[4][4] = {};

  stage(0, 0);
  __syncthreads();
  int cur = 0;
  const int NT = DM / 32;  // 24
  for (int t = 0; t < NT; ++t) {
    if (t + 1 < NT) stage((t + 1) * 32, cur ^ 1);
    s16x8 af[4], bfr[4];
    for (int i = 0; i < 4; i++)
      af[i] = *(const s16x8*)&As[cur * 4096 + (wm + i * 16 + l15) * 32 + quad * 8];
    for (int j = 0; j < 4; j++)
      bfr[j] = *(const s16x8*)&Bs[cur * 4096 + (wn + j * 16 + l15) * 32 + quad * 8];
    for (int i = 0; i < 4; i++)
      for (int j = 0; j < 4; j++)
        acc[i][j] = MFMA16(af[i], bfr[j], acc[i][j]);
    __syncthreads();
    cur ^= 1;
  }

  const int mat = n0 / DM;  // uniform per block (768 % 128 == 0)
  if (mat == 2) {
    // ---- V epilogue: transpose via LDS, coalesced Vt stores ----
    // VT[c_local (64)][s_local (128)], stride 136 (16-B aligned rows, low
    // bank conflict). Two half-passes over c: waves with wn==half*64 write.
    bf16* VT = smem;  // 64*136 elems = 17408 B <= 32768 B, LDS dead now
    const int bb = m0 >> 11;          // whole block in one batch
    const int s_base = m0 & 2047;
    for (int half = 0; half < 2; ++half) {
      if ((wave >> 1) == half) {
        for (int j = 0; j < 4; j++) {
          int cc = n0 - 2 * DM + wn + j * 16 + l15;
          float bsv = bV[cc];
          unsigned* row = (unsigned*)&VT[(j * 16 + l15) * 136];
          for (int i = 0; i < 4; i++) {
            int sl = wm + i * 16 + quad * 4;
            row[(sl >> 1) + 0] = pkbf16(acc[i][j][0] + bsv, acc[i][j][1] + bsv);
            row[(sl >> 1) + 1] = pkbf16(acc[i][j][2] + bsv, acc[i][j][3] + bsv);
          }
        }
      }
      __syncthreads();
      for (int k = 0; k < 4; ++k) {
        int idx = tid + k * 256;
        int cl = idx >> 4, sq = (idx & 15) << 3;
        int cc = n0 - 2 * DM + half * 64 + cl;
        int head = cc >> 6, hh = cc & 63;
        int bh = bb * NH + head;
        *(s16x8*)(Vt + ((size_t)bh * DH + hh) * SEQ + s_base + sq) =
            *(const s16x8*)&VT[cl * 136 + sq];
      }
      __syncthreads();
    }
    return;
  }

  for (int j = 0; j < 4; j++) {
    int col = n0 + wn + j * 16 + l15;
    int cc = col - mat * DM;
    int head = cc >> 6, h = cc & 63;
    float bsv = ((mat == 0) ? bQ : bK)[cc];
    for (int i = 0; i < 4; i++) {
      int row0 = m0 + wm + i * 16 + quad * 4;
      int b = row0 >> 11;
      int s = row0 & 2047;
      int bh = b * NH + head;
      const float scale = (mat == 0) ? (0.125f * LOG2E) : 1.0f;
      bf16* dst = ((mat == 0) ? Qb : Kb) + ((size_t)bh * SEQ + s) * DH + h;
      for (int r = 0; r < 4; r++)
        dst[(size_t)r * DH] = __float2bfloat16((acc[i][j][r] + bsv) * scale);
    }
  }
}

// ---------------------------------------------------------------------------
// Kernel 3: flash attention (causal) — EXACT round-0 configuration
// (58.6 us measured): LDS P round-trip, linear decode, LDS 27648 B. CONTROL.
// ---------------------------------------------------------------------------
__global__ __launch_bounds__(256) void flash_kernel(
    const bf16* __restrict__ Qb, const bf16* __restrict__ Kb,
    const bf16* __restrict__ Vt, bf16* __restrict__ Z) {
  __shared__ bf16 Ks[64 * 72];    // [key][h], padded
  __shared__ bf16 VsT[64 * 72];   // [h][key], padded
  __shared__ bf16 Ps[4][16 * 72]; // per-wave P [q][key], padded

  const int bh = blockIdx.x >> 4;  // 0..47
  const int p = blockIdx.x & 15;   // 0..15
  const int qtA = 31 - p, qtB = p;
  const int b = bh / NH, head = bh % NH;
  const int tid = threadIdx.x;
  const int wave = tid >> 6, lane = tid & 63;
  const int quad = lane >> 4, l15 = lane & 15;
  const int qwA = qtA * 64 + wave * 16;  // this wave's 16 q rows (tile A)
  const int qwB = qtB * 64 + wave * 16;  // tile B

  const bf16* Kbase = Kb + (size_t)bh * SEQ * DH;
  const bf16* Vbase = Vt + (size_t)bh * DH * SEQ;

  // Q as B-operand: lane n=l15 -> q=qw+l15, k -> h (pre-scaled 0.125*log2e).
  s16x8 bqA[2], bqB[2];
  for (int ks = 0; ks < 2; ks++) {
    bqA[ks] = *(const s16x8*)(Qb +
        ((size_t)bh * SEQ + qwA + l15) * DH + ks * 32 + quad * 8);
    bqB[ks] = *(const s16x8*)(Qb +
        ((size_t)bh * SEQ + qwB + l15) * DH + ks * 32 + quad * 8);
  }

  f32x4 oA[4] = {}, oB[4] = {};
  float lA = 0.f, lB = 0.f;

  // staging: 256 threads x 2 chunks (16B) per matrix
  s16x8 kr[2], vr[2];
  auto load_tile = [&](int kt) {
    const int kbase = kt * 64;
    for (int u = 0; u < 2; u++) {
      int c = tid + u * 256;
      int row = c >> 3, seg = (c & 7) << 3;
      kr[u] = *(const s16x8*)(Kbase + (size_t)(kbase + row) * DH + seg);
      vr[u] = *(const s16x8*)(Vbase + (size_t)row * SEQ + kbase + seg);
    }
  };
  auto store_tile = [&]() {
    for (int u = 0; u < 2; u++) {
      int c = tid + u * 256;
      int row = c >> 3, seg = (c & 7) << 3;
      *(s16x8*)&Ks[row * 72 + seg] = kr[u];
      *(s16x8*)&VsT[row * 72 + seg] = vr[u];
    }
  };

  auto compute = [&](int kt, const s16x8 bq[2], f32x4 o[4], float& l_i,
                     int qw, bool diag) {
    const int kbase = kt * 64;
    // S^T[key][q]: A=K (m=key), B=Q (n=q). s[ktf]: key=kbase+ktf*16+quad*4+r,
    // q = qw + l15.
    f32x4 s[4] = {};
    for (int ks = 0; ks < 2; ks++) {
      s16x8 ak[4];
      for (int ktf = 0; ktf < 4; ktf++)
        ak[ktf] = *(const s16x8*)&Ks[(ktf * 16 + l15) * 72 + ks * 32 + quad * 8];
      for (int ktf = 0; ktf < 4; ktf++)
        s[ktf] = MFMA16(ak[ktf], bq[ks], s[ktf]);
    }

    if (diag) {  // causal mask on the diagonal tile
      int qg = qw + l15;
      for (int ktf = 0; ktf < 4; ktf++)
        for (int r = 0; r < 4; r++) {
          int kg = kbase + ktf * 16 + quad * 4 + r;
          if (kg > qg) s[ktf][r] = -1e30f;
        }
    }

    // softmax numerator: p = exp2(s) (bounded; masked -> 0); per-lane partial l
    float rs = 0.f;
    for (int ktf = 0; ktf < 4; ktf++)
      for (int r = 0; r < 4; r++) {
        float pv = fast_exp2(s[ktf][r]);
        s[ktf][r] = pv;
        rs += pv;
      }
    l_i += rs;

    // P -> per-wave LDS in [q][key] (A-operand friendly)
    bf16* Pw = Ps[wave];
    for (int ktf = 0; ktf < 4; ktf++) {
      uint2 w;
      w.x = pkbf16(s[ktf][0], s[ktf][1]);
      w.y = pkbf16(s[ktf][2], s[ktf][3]);
      *(uint2*)&Pw[l15 * 72 + ktf * 16 + quad * 4] = w;
    }
    asm volatile("s_waitcnt lgkmcnt(0)" ::: "memory");

    // PV: o[q][h] += P[q][key] * V^T[h][key]
    for (int ks2 = 0; ks2 < 2; ks2++) {
      s16x8 ap = *(const s16x8*)&Pw[l15 * 72 + ks2 * 32 + quad * 8];
      for (int hf = 0; hf < 4; hf++) {
        s16x8 bv =
            *(const s16x8*)&VsT[(hf * 16 + l15) * 72 + ks2 * 32 + quad * 8];
        o[hf] = MFMA16(ap, bv, o[hf]);
      }
    }
  };

  load_tile(0);
  for (int kt = 0; kt <= qtA; kt++) {
    __syncthreads();
    store_tile();
    __syncthreads();
    if (kt < qtA) load_tile(kt + 1);
    compute(kt, bqA, oA, lA, qwA, kt == qtA);
    if (kt <= qtB) compute(kt, bqB, oB, lB, qwB, kt == qtB);
  }

  // epilogue: reduce l across quads, broadcast 1/l to C/D rows, write Z
  auto epilogue = [&](f32x4 o[4], float l_i, int qw) {
    float lv = l_i;
    lv += __shfl_xor(lv, 16, 64);
    lv += __shfl_xor(lv, 32, 64);
    float linv = 1.f / lv;
    for (int r = 0; r < 4; r++) {
      float li = __shfl(linv, (lane & 48) | (quad * 4 + r), 64);
      int q = qw + quad * 4 + r;
      for (int hf = 0; hf < 4; hf++) {
        Z[((size_t)b * SEQ + q) * DM + head * DH + hf * 16 + l15] =
            __float2bfloat16(o[hf][r] * li);
      }
    }
  };
  epilogue(oA, lA, qwA);
  epilogue(oB, lB, qwB);
}

// ---------------------------------------------------------------------------
// Kernel 4: output projection (2-phase double-buffer, unchanged from round 3).
// ---------------------------------------------------------------------------
__global__ __launch_bounds__(256) void out_gemm(
    const bf16* __restrict__ Z, const bf16* __restrict__ WoT,
    const float* __restrict__ bO, float* __restrict__ out) {
  __shared__ bf16 As[2][128 * 32];
  __shared__ bf16 Bs[2][128 * 32];
  const int m0 = blockIdx.x * 128;
  const int n0 = blockIdx.y * 128;
  const int tid = threadIdx.x;
  const int wave = tid >> 6, lane = tid & 63;
  const int quad = lane >> 4, l15 = lane & 15;
  const int wm = (wave & 1) * 64, wn = (wave >> 1) * 64;

  const int r0 = tid >> 2, sg0 = (tid & 3) << 3;
  const int c1 = tid + 256, r1 = c1 >> 2, sg1 = (c1 & 3) << 3;

  auto stage = [&](int k0, int buf) {
    gl2lds16(Z + (size_t)(m0 + r0) * DM + k0 + sg0, &As[buf][tid * 8]);
    gl2lds16(WoT + (size_t)(n0 + r0) * DM + k0 + sg0, &Bs[buf][tid * 8]);
    gl2lds16(Z + (size_t)(m0 + r1) * DM + k0 + sg1, &As[buf][c1 * 8]);
    gl2lds16(WoT + (size_t)(n0 + r1) * DM + k0 + sg1, &Bs[buf][c1 * 8]);
  };

  f32x4 acc[4][4] = {};

  stage(0, 0);
  __syncthreads();
  int cur = 0;
  const int NT = DM / 32;  // 24
  for (int t = 0; t < NT; ++t) {
    if (t + 1 < NT) stage((t + 1) * 32, cur ^ 1);
    s16x8 af[4], bfr[4];
    for (int i = 0; i < 4; i++)
      af[i] = *(const s16x8*)&As[cur][(wm + i * 16 + l15) * 32 + quad * 8];
    for (int j = 0; j < 4; j++)
      bfr[j] = *(const s16x8*)&Bs[cur][(wn + j * 16 + l15) * 32 + quad * 8];
    for (int i = 0; i < 4; i++)
      for (int j = 0; j < 4; j++)
        acc[i][j] = MFMA16(af[i], bfr[j], acc[i][j]);
    __syncthreads();
    cur ^= 1;
  }

  for (int j = 0; j < 4; j++) {
    int col = n0 + wn + j * 16 + l15;
    float bv = bO[col];
    for (int i = 0; i < 4; i++)
      for (int r = 0; r < 4; r++) {
        int row = m0 + wm + i * 16 + quad * 4 + r;
        out[(size_t)row * DM + col] = acc[i][j][r] + bv;
      }
  }
}

// ---------------------------------------------------------------------------
extern "C" void kernel_launch(void* const* d_in, const int* in_sizes, int n_in,
                              void* d_out, int out_size, void* d_ws,
                              size_t ws_size, hipStream_t stream) {
  const float* x  = (const float*)d_in[0];
  const float* wq = (const float*)d_in[1];
  const float* wk = (const float*)d_in[2];
  const float* wv = (const float*)d_in[3];
  const float* wo = (const float*)d_in[4];
  const float* bq = (const float*)d_in[5];
  const float* bk = (const float*)d_in[6];
  const float* bv = (const float*)d_in[7];
  const float* bo = (const float*)d_in[8];
  float* out = (float*)d_out;

  bf16* WcT = (bf16*)d_ws;                    // 2304*768
  bf16* WoT = WcT + (size_t)QKVC * DM;        //  768*768
  bf16* Qb  = WoT + (size_t)DM * DM;          // 8192*768
  bf16* Kb  = Qb + (size_t)ROWS * DM;         // 8192*768
  bf16* Vt  = Kb + (size_t)ROWS * DM;         // 8192*768 ([bh][h][s])
  bf16* xbZ = Vt + (size_t)ROWS * DM;         // 8192*768 (xb, then Z)

  prep_all<<<NTWC + NTWO + NXB, 256, 0, stream>>>(
      wq, wk, wv, wo, x, WcT, WoT, xbZ);
  qkv_gemm<<<dim3(ROWS / 128, QKVC / 128), 256, 0, stream>>>(
      xbZ, WcT, bq, bk, bv, Qb, Kb, Vt);
  flash_kernel<<<48 * 16, 256, 0, stream>>>(Qb, Kb, Vt, xbZ);
  out_gemm<<<dim3(ROWS / 128, DM / 128), 256, 0, stream>>>(xbZ, WoT, bo, out);
}